// Round 14
// baseline (759.616 us; speedup 1.0000x reference)
//
#include <hip/hip_runtime.h>
#include <cfloat>
#include <climits>
#include <cstdint>

#define HH 1024
#define WW 2048
#define NPIX (HH * WW)
#define NWORD (NPIX / 64)
#define UNROLL 4
#define MAXI 200

#define BAND_LO 0.693130f
#define BAND_HI 0.693160f
#define LN2_CMP 0.6931472f

// ================= FAT layout =================
#define NBLK 256                     // cluster blocks (barrier width)
#define CTPB 1024                    // cluster threads/block (16 waves; 4096 waves total)
#define PREB 1024                    // precompute blocks
#define PTPB 256
#define PWPB (NWORD / PREB)          // 32 words per precompute block
#define WPB  (NWORD / NBLK)          // 128 words per cluster block (recon map)
#define WPW  (WPB * 64 / CTPB)       // 8 words per wave in recon

#define F_CTL  ((size_t)0x0)         // 1024 slots x 128B; scalars/CSUM/NOW after
#define FC_CNT   32768               // int index
#define FC_A0KEY 32770               // u64 (8-aligned)
#define FC_NOW   32800               // 256 ints
#define FC_CSUM  33280               // 1024 ints
#define FC_MEMSET_BYTES ((size_t)0x22000)
#define F_PV   ((size_t)0x22000)     // 2 par x 256 u64
#define F_PSA  ((size_t)0x24000)
#define F_PSB  ((size_t)0x26000)
#define F_MASK ((size_t)0x40000)     // 256 KB mask bitwords
#define F_WOFF ((size_t)0x80000)     // 128 KB per-word compacted base
#define F_UNCL ((size_t)0xA0000)     // compacted uncl bits (wave-private, loop map)
#define F_P1C  ((size_t)0xE0000)     // compacted prop1 bits (wave-private, loop map)
#define CMAX   1220000
#define F_CEXY ((size_t)0x120000)                    // float2
#define F_CSV  (F_CEXY + (size_t)CMAX * 8 + 512)     // float
#define F_CSM  (F_CSV + (size_t)CMAX * 4 + 512)      // float
#define F_CS2  (F_CSM + (size_t)CMAX * 4 + 512)      // float2
#define FAT_NEED ((size_t)0x2200000)

// ================= THIN fallback (round-6 proven) =================
#define T_MASK ((size_t)0x0)
#define T_UNCL ((size_t)0x40000)
#define T_P1   ((size_t)0x80000)
#define T_PV   ((size_t)0xC0000)
#define T_PSA  ((size_t)0xC2000)
#define T_PSB  ((size_t)0xC4000)
#define T_CTL  ((size_t)0xD0000)
#define T_NBLK 256
#define TPB 256
#define TC_REL  8192
#define TC_NOW  8256
#define TC_ZEND 16384

// ---- relaxed agent-scope atomics: bypass non-coherent per-XCD L2, complete at
// the coherence point. No acq/rel -> no cache maintenance; ordering comes from
// vmcnt(0) drains + the slot observation chain.
__device__ __forceinline__ int al(const int* p) {
  return __hip_atomic_load((int*)p, __ATOMIC_RELAXED, __HIP_MEMORY_SCOPE_AGENT);
}
__device__ __forceinline__ void as_(int* p, int v) {
  __hip_atomic_store(p, v, __ATOMIC_RELAXED, __HIP_MEMORY_SCOPE_AGENT);
}
__device__ __forceinline__ uint64_t al64(const uint64_t* p) {
  return __hip_atomic_load((uint64_t*)p, __ATOMIC_RELAXED, __HIP_MEMORY_SCOPE_AGENT);
}
__device__ __forceinline__ void as64(uint64_t* p, uint64_t v) {
  __hip_atomic_store(p, v, __ATOMIC_RELAXED, __HIP_MEMORY_SCOPE_AGENT);
}

// seed_map = softmax(pred[5:7], axis=0)[1], op-for-op (max-subtract)
__device__ __forceinline__ float compute_sm(const float* __restrict__ pred, int i) {
  float a = pred[(size_t)5 * NPIX + i];
  float b = pred[(size_t)6 * NPIX + i];
  float m = fmaxf(a, b);
  float ea = expf(a - m);
  float eb = expf(b - m);
  return eb / (ea + eb);
}

__device__ __forceinline__ void compute_emb(const float* __restrict__ pred, int i,
                                            float& ex, float& ey) {
#pragma clang fp contract(off)
  int r = i >> 11;
  int c = i & (WW - 1);
  float xm = (float)c * (2.0f / 2047.0f);
  float ym = (float)r * (1.0f / 1023.0f);
  ex = tanhf(pred[i]) + xm;
  ey = tanhf(pred[(size_t)NPIX + i]) + ym;
}

// z in the reference's exact association; decision expf(-z)>0.5
__device__ __forceinline__ float prop_z(float ex, float ey, float cx, float cy,
                                        float sx, float sy) {
#pragma clang fp contract(off)
  float dx = ex - cx;
  float dy = ey - cy;
  float t0 = dx * dx; t0 = t0 * sx;
  float t1 = dy * dy; t1 = t1 * sy;
  return t0 + t1;
}

__device__ __forceinline__ bool prop_test(float ex, float ey, float cx, float cy,
                                          float sx, float sy) {
  float z = prop_z(ex, ey, cx, cy, sx, sy);
  return expf(-z) > 0.5f;
}

__device__ __forceinline__ uint64_t sh64(uint64_t v, int m) {
  return (uint64_t)__shfl_xor((unsigned long long)v, m, 64);
}

// block reduce: key = max (packed (val_bits<<32)|~idx), sa/sb u64 sums.
template <int T>
__device__ __forceinline__ void bred(uint64_t& key, uint64_t& sa, uint64_t& sb,
                                     uint64_t* lK, uint64_t* lA, uint64_t* lB) {
#pragma unroll
  for (int m = 1; m < 64; m <<= 1) {
    uint64_t k2 = sh64(key, m); if (k2 > key) key = k2;
    sa += sh64(sa, m);
    sb += sh64(sb, m);
  }
  int wid = threadIdx.x >> 6;
  if ((threadIdx.x & 63) == 0) { lK[wid] = key; lA[wid] = sa; lB[wid] = sb; }
  __syncthreads();
  key = lK[0]; sa = lA[0]; sb = lB[0];
#pragma unroll
  for (int w = 1; w < T / 64; w++) {
    uint64_t k2 = lK[w]; if (k2 > key) key = k2;
    sa += lA[w];
    sb += lB[w];
  }
  __syncthreads();
}

// redundant global reduce over per-block partials (every block, identical order)
template <int T>
__device__ __forceinline__ void gred(const uint64_t* PVp, const uint64_t* PAp,
                                     const uint64_t* PBp, int nblk,
                                     uint64_t& key, uint64_t& sa, uint64_t& sb,
                                     uint64_t* lK, uint64_t* lA, uint64_t* lB) {
  key = 0; sa = 0; sb = 0;
  for (int b = threadIdx.x; b < nblk; b += T) {
    uint64_t k2 = al64(&PVp[b]); if (k2 > key) key = k2;
    sa += al64(&PAp[b]);
    sb += al64(&PBp[b]);
  }
  bred<T>(key, sa, sb, lK, lA, lB);
}

// decentralized slot barrier: arrive (own slot), every block's wave 0 polls all.
__device__ __forceinline__ void gbar_d(int* CTL, int nblk, int ph) {
  __syncthreads();   // drains vmcnt -> prior stores L3-visible before slot store
  if (threadIdx.x == 0) {
    asm volatile("s_waitcnt vmcnt(0)" ::: "memory");
    as_(&CTL[blockIdx.x * 32], ph);
  }
  if (threadIdx.x < 64) {
    for (;;) {
      bool ok = true;
      for (int b = (int)threadIdx.x; b < nblk; b += 64)
        ok &= (al(&CTL[b * 32]) >= ph);
      if (__all(ok)) break;
      __builtin_amdgcn_s_sleep(1);
    }
    asm volatile("" ::: "memory");
  }
  __syncthreads();
}

// ============ FAT precompute: ONE cooperative kernel (plain-store scatter) ============
// 1024 blocks x 256 thr, all co-resident. Order-preserving compaction: block-
// private mask words (LDS), agent-posted chunk sums, slot barrier, redundant
// scan, then scatter with PLAIN stores (published by the kernel-end flush —
// the consumer is the NEXT kernel, so no agent atomics needed in the scatter).
__global__ __launch_bounds__(PTPB) void preC_fat(const float* __restrict__ pred,
                                                 char* __restrict__ ws) {
  uint64_t* MASKW = (uint64_t*)(ws + F_MASK);
  uint32_t* WOFF = (uint32_t*)(ws + F_WOFF);
  uint64_t* UNCLC = (uint64_t*)(ws + F_UNCL);
  float2* CEXY = (float2*)(ws + F_CEXY);
  float* CSV = (float*)(ws + F_CSV);
  float* CSM = (float*)(ws + F_CSM);
  float2* CS2 = (float2*)(ws + F_CS2);
  int* CTL = (int*)(ws + F_CTL);

  const int tid = threadIdx.x;
  const int lane = tid & 63;
  const int wv = tid >> 6;
  const int b = blockIdx.x;

  __shared__ uint64_t warr[PWPB];
  __shared__ int pcs[PWPB];
  __shared__ int lw[4];
  __shared__ int s_base;
  __shared__ int s_woff[PWPB];
  __shared__ uint64_t lKk[4];

  // phase 1: mask words for this block's 32-word chunk (block-private)
  for (int k = 0; k < PWPB / 4; k++) {
    int wl = wv * (PWPB / 4) + k;
    int w = b * PWPB + wl;
    int i = (w << 6) | lane;
    float smv = compute_sm(pred, i);
    uint64_t bal = __ballot(smv > 0.5f);
    if (lane == 0) { MASKW[w] = bal; warr[wl] = bal; pcs[wl] = (int)__popcll(bal); }
  }
  // UNCLC bulk all-ones (tail beyond cnt handled by j<cnt guard in pass C)
  {
    int gid = b * PTPB + tid;
    for (int w = gid; w < (CMAX + 63) / 64; w += PREB * PTPB) UNCLC[w] = ~0ull;
  }
  __syncthreads();
  if (tid == 0) {
    int t = 0;
#pragma unroll
    for (int k = 0; k < PWPB; k++) t += pcs[k];
    as_(&CTL[FC_CSUM + b], t);       // agent: read cross-block after barrier
  }
  gbar_d(CTL, PREB, 1);

  // phase 2: redundant scan of 1024 chunk sums -> own base
  {
    int base4[4];
    int s = 0;
#pragma unroll
    for (int k = 0; k < 4; k++) {
      int v = al(&CTL[FC_CSUM + tid * 4 + k]);
      base4[k] = s; s += v;
    }
    int inc = s;
#pragma unroll
    for (int off = 1; off < 64; off <<= 1) {
      int v = __shfl_up(inc, off, 64);
      if (lane >= off) inc += v;
    }
    if (lane == 63) lw[wv] = inc;
    __syncthreads();
    if (tid == 0) {
      int run = 0;
#pragma unroll
      for (int k = 0; k < 4; k++) { int v = lw[k]; lw[k] = run; run += v; }
      if (b == 0) CTL[FC_CNT] = run;   // plain: consumed by next kernel
    }
    __syncthreads();
    int excl = lw[wv] + inc - s;       // exclusive prefix of this thread's group
#pragma unroll
    for (int k = 0; k < 4; k++)
      if (tid * 4 + k == b) s_base = excl + base4[k];
  }
  __syncthreads();
  // per-word exclusive offsets within the chunk (lane-scan over 32 counts)
  if (tid < PWPB) {
    int pc = pcs[tid];
    int inc = pc;
#pragma unroll
    for (int off = 1; off < PWPB; off <<= 1) {
      int v = __shfl_up(inc, off, 32);
      if (tid >= off) inc += v;
    }
    int excl = s_base + inc - pc;
    s_woff[tid] = excl;
    WOFF[b * PWPB + tid] = (uint32_t)excl;   // plain
  }
  __syncthreads();

  // scatter SoA (plain stores) + A0 argmax fold
  uint64_t key = 0;
  for (int k = 0; k < PWPB / 4; k++) {
    int wl = wv * (PWPB / 4) + k;
    int w = b * PWPB + wl;
    uint64_t mw = warr[wl];
    if ((mw >> lane) & 1ull) {
      int i = (w << 6) | lane;
      int j = s_woff[wl] + (int)__popcll(mw & ((1ull << lane) - 1ull));
      if (j < CMAX) {
        float ex, ey; compute_emb(pred, i, ex, ey);
        float smv = compute_sm(pred, i);
        float sv = 1.0f / (1.0f + expf(-pred[(size_t)4 * NPIX + i]));
        float sx = expf(pred[(size_t)2 * NPIX + i] * 10.0f);
        float sy = expf(pred[(size_t)3 * NPIX + i] * 10.0f);
        CEXY[j] = make_float2(ex, ey);
        CSV[j] = sv;
        CSM[j] = smv;
        CS2[j] = make_float2(sx, sy);
        uint64_t k2 = ((uint64_t)(uint32_t)__float_as_int(smv) << 32) | (uint32_t)~(uint32_t)j;
        if (k2 > key) key = k2;
      }
    }
  }
#pragma unroll
  for (int m = 1; m < 64; m <<= 1) {
    uint64_t k2 = sh64(key, m); if (k2 > key) key = k2;
  }
  if (lane == 0) lKk[wv] = key;
  __syncthreads();
  if (tid == 0) {
    uint64_t k = lKk[0];
#pragma unroll
    for (int w = 1; w < 4; w++) if (lKk[w] > k) k = lKk[w];
    if (k) __hip_atomic_fetch_max((unsigned long long*)&CTL[FC_A0KEY], (unsigned long long)k,
                                  __ATOMIC_RELAXED, __HIP_MEMORY_SCOPE_AGENT);
  }
}

// ======================= FAT main cooperative kernel (1024 thr x 256 blk) =======================
__global__ __launch_bounds__(CTPB) void cluster_fat(const float* __restrict__ pred,
                                                    int* __restrict__ out,
                                                    char* __restrict__ ws) {
  uint64_t* MASKW = (uint64_t*)(ws + F_MASK);
  uint32_t* WOFF = (uint32_t*)(ws + F_WOFF);
  uint64_t* UNCLC = (uint64_t*)(ws + F_UNCL);
  uint64_t* P1C = (uint64_t*)(ws + F_P1C);
  uint64_t* PV = (uint64_t*)(ws + F_PV);
  uint64_t* PSA = (uint64_t*)(ws + F_PSA);
  uint64_t* PSB = (uint64_t*)(ws + F_PSB);
  int* CTL = (int*)(ws + F_CTL);
  const float2* __restrict__ CEXY = (const float2*)(ws + F_CEXY);
  const float* __restrict__ CSV = (const float*)(ws + F_CSV);
  const float* __restrict__ CSM = (const float*)(ws + F_CSM);
  const float2* __restrict__ CS2 = (const float2*)(ws + F_CS2);

  const int tid = threadIdx.x;
  const int lane = tid & 63;
  const int wid = tid >> 6;
  const int bid = blockIdx.x;
  const int nw = NBLK * (CTPB / 64);        // 4096 waves
  const int gw0 = bid * (CTPB / 64) + wid;

  __shared__ uint64_t lK[CTPB / 64], lA[CTPB / 64], lB[CTPB / 64];
  __shared__ int lbin[256];
  __shared__ float s_cx[MAXI], s_cy[MAXI], s_sx[MAXI], s_sy[MAXI];
  __shared__ int s_sz[MAXI];

  int cnt = al(&CTL[FC_CNT]);
  if (cnt > CMAX) cnt = CMAX;
  const int cnw = (cnt + 63) >> 6;

  int ph = 1;   // preC_fat consumed phase 1 on slots 0..255

  // A0 from preC_fat's atomic max
  uint64_t akey = al64((const uint64_t*)&CTL[FC_A0KEY]);
  float val1 = __int_as_float((int)(akey >> 32));
  int seed1 = (int)~(uint32_t)akey;
  int Sall = cnt;
  float cx1, cy1, sx1, sy1;
  {
    int j = (seed1 >= 0 && seed1 < cnt) ? seed1 : 0;
    float2 e = CEXY[j]; float2 r = CS2[j];
    cx1 = e.x; cy1 = e.y; sx1 = r.x; sy1 = r.y;
  }

  int count = 1, it = 0;
  while (Sall > 160 && count < 200 && it < 2000) {
    if (val1 < 0.5f) break;   // 'stop': freeze state

    // ---- pass B: prop1 bits, cnt1, seed2 = argmax(sv | prop1) ----
    {
      int par = (ph + 1) & 1;
      uint64_t key = 0, sa = 0, sb = 0;
      for (int w0 = gw0; w0 < cnw; w0 += nw * UNROLL) {
#pragma unroll
        for (int u = 0; u < UNROLL; u++) {
          int w = w0 + u * nw;
          if (w >= cnw) continue;
          int j = (w << 6) | lane;
          float z = 1e30f;
          if (j < cnt) {
            float2 e = CEXY[j];
            z = prop_z(e.x, e.y, cx1, cy1, sx1, sy1);
          }
          bool band = (z > BAND_LO) & (z < BAND_HI);
          bool p;
          if (__any(band)) p = (j < cnt) && (expf(-z) > 0.5f);
          else p = z < LN2_CMP;
          uint64_t r = __ballot(p);
          if (lane == 0) P1C[w] = r;   // plain: wave-private
          if (p) {
            sa++;
            float sv = CSV[j];          // gated: only prop1 members
            uint64_t k2 = ((uint64_t)(uint32_t)__float_as_int(sv) << 32) | (uint32_t)~(uint32_t)j;
            if (k2 > key) key = k2;
          }
        }
      }
      bred<CTPB>(key, sa, sb, lK, lA, lB);
      if (tid == 0) {
        as64(&PV[par * NBLK + bid], key);
        as64(&PSA[par * NBLK + bid], sa);
        as64(&PSB[par * NBLK + bid], sb);
      }
    }
    gbar_d(CTL, NBLK, ++ph);
    int seed2, cnt1;
    {
      int par = ph & 1;
      uint64_t key, sa, sb;
      gred<CTPB>(PV + par * NBLK, PSA + par * NBLK, PSB + par * NBLK, NBLK,
                 key, sa, sb, lK, lA, lB);
      seed2 = (int)~(uint32_t)key;
      cnt1 = (int)sa;
    }
    bool big1 = cnt1 > 160;
    float cx2, cy2, sx2, sy2;
    {
      int j = (seed2 >= 0 && seed2 < cnt) ? seed2 : 0;
      float2 e = CEXY[j]; float2 r = CS2[j];
      cx2 = e.x; cy2 = e.y; sx2 = r.x; sy2 = r.y;
    }

    // ---- pass C (fused): prop2 counts/overlap (seed corrections inline) +
    //      uncl update + next-iteration argmax/sum ----
    {
      int par = (ph + 1) & 1;
      uint64_t key = 0, sa = 0, sb = 0;
      for (int w0 = gw0; w0 < cnw; w0 += nw * UNROLL) {
#pragma unroll
        for (int u = 0; u < UNROLL; u++) {
          int w = w0 + u * nw;
          if (w >= cnw) continue;
          uint64_t uw = UNCLC[w];                 // plain: wave-private
          uint64_t p1w = big1 ? 0ull : P1C[w];
          int j = (w << 6) | lane;
          float z = 1e30f;
          if (j < cnt) {
            float2 e = CEXY[j];
            z = prop_z(e.x, e.y, cx2, cy2, sx2, sy2);
          }
          bool band = (z > BAND_LO) & (z < BAND_HI);
          bool p;
          if (__any(band)) p = (j < cnt) && (expf(-z) > 0.5f);
          else p = z < LN2_CMP;
          bool ub = ((uw >> lane) & 1ull) != 0;
          // reference clears uncl at seed1 (always) and seed2 (if big1) BEFORE
          // the overlap sum -> owning lane doesn't count its overlap.
          if (p) {
            sa += 1ull;
            if (ub && j != seed1 && !(big1 && j == seed2)) sa += (1ull << 32);
          }
          bool fp = big1 ? p : (((p1w >> lane) & 1ull) != 0);
          bool nu = ub && (j < cnt) && !(fp || j == seed1 || (big1 && j == seed2));
          uint64_t r = __ballot(nu);
          if (lane == 0 && uw) UNCLC[w] = r;      // plain: wave-private
          if (nu) {
            sb++;
            float smv = CSM[j];                    // gated: only uncl survivors
            uint64_t k2 = ((uint64_t)(uint32_t)__float_as_int(smv) << 32) | (uint32_t)~(uint32_t)j;
            if (k2 > key) key = k2;
          }
        }
      }
      bred<CTPB>(key, sa, sb, lK, lA, lB);
      if (tid == 0) {
        as64(&PV[par * NBLK + bid], key);
        as64(&PSA[par * NBLK + bid], sa);
        as64(&PSB[par * NBLK + bid], sb);
      }
    }
    gbar_d(CTL, NBLK, ++ph);
    {
      int par = ph & 1;
      uint64_t key, sa, sb;
      gred<CTPB>(PV + par * NBLK, PSA + par * NBLK, PSB + par * NBLK, NBLK,
                 key, sa, sb, lK, lA, lB);
      int cnt2 = (int)(uint32_t)sa;
      int ovl = (int)(uint32_t)(sa >> 32);
      bool big2 = cnt2 > 160;
      int den = cnt2 > 1 ? cnt2 : 1;
      float ratio = (float)ovl / (float)den;
      bool accept = big1 && big2 && (ratio > 0.5f);
      if (accept) {
        if (tid == 0) {
          s_cx[count] = cx2; s_cy[count] = cy2;
          s_sx[count] = sx2; s_sy[count] = sy2;
          s_sz[count] = cnt2;
        }
        count++;
      }
      it++;
      val1 = __int_as_float((int)(key >> 32));
      seed1 = (int)~(uint32_t)key;
      Sall = (int)sb;
    }
    {
      int j = (seed1 >= 0 && seed1 < cnt) ? seed1 : 0;
      float2 e = CEXY[j]; float2 r = CS2[j];
      cx1 = e.x; cy1 = e.y; sx1 = r.x; sy1 = r.y;
    }
  }

  // ---- reconstruction (pixel space, contiguous map): out + zero-fill + bincount ----
  if (tid < 256) lbin[tid] = 0;
  __syncthreads();   // publishes tid0's s_* log writes block-wide
  for (int k = 0; k < WPW; k++) {
    int w = bid * WPB + wid * WPW + k;
    uint64_t mw = MASKW[w];
    int i = (w << 6) | lane;
    int id = 0;
    if ((mw >> lane) & 1ull) {
      int j = (int)WOFF[w] + (int)__popcll(mw & ((1ull << lane) - 1ull));
      if (j < CMAX) {
        float2 e = CEXY[j];
        for (int kk = 1; kk < count; kk++) {
          float z = prop_z(e.x, e.y, s_cx[kk], s_cy[kk], s_sx[kk], s_sy[kk]);
          bool band = (z > BAND_LO) & (z < BAND_HI);
          bool p;
          if (__any(band)) p = expf(-z) > 0.5f;
          else p = z < LN2_CMP;
          if (p) id = kk;
        }
      }
      atomicAdd(&lbin[id], 1);
    }
    out[i] = id;   // full-word coalesced store (zero-fill fused)
  }
  __syncthreads();
  if (tid < 256 && lbin[tid] > 0)
    __hip_atomic_fetch_add(&CTL[FC_NOW + tid], lbin[tid], __ATOMIC_RELAXED,
                           __HIP_MEMORY_SCOPE_AGENT);
  gbar_d(CTL, NBLK, ++ph);
  if (tid < 256) lbin[tid] = al(&CTL[FC_NOW + tid]);
  __syncthreads();
  for (int k = 0; k < WPW; k++) {
    int w = bid * WPB + wid * WPW + k;
    int i = (w << 6) | lane;
    int id = out[i];   // plain: same wave wrote it
    if (id > 0) {
      int n = lbin[id];
      int sz = s_sz[id];
      bool rm = (n != sz) && ((n < 480) || ((float)n < 0.5f * (float)sz));
      if (rm) out[i] = 0;
    }
  }
}

// ======================= THIN fallback (round-6, proven) =======================
__device__ __forceinline__ void gbar_rel(int* CTL, int nblk, int ph) {
  __syncthreads();
  if (threadIdx.x == 0) {
    asm volatile("s_waitcnt vmcnt(0)" ::: "memory");
    as_(&CTL[blockIdx.x * 32], ph);
  }
  if (blockIdx.x == 0) {
    if (threadIdx.x < 64) {
      for (;;) {
        bool ok = true;
        for (int b = (int)threadIdx.x; b < nblk; b += 64)
          ok &= (al(&CTL[b * 32]) >= ph);
        if (__all(ok)) break;
        __builtin_amdgcn_s_sleep(1);
      }
      asm volatile("" ::: "memory");
      if (threadIdx.x == 0) as_(&CTL[TC_REL], ph);
    }
  } else {
    if (threadIdx.x == 0) {
      while (al(&CTL[TC_REL]) < ph) __builtin_amdgcn_s_sleep(1);
      asm volatile("" ::: "memory");
    }
  }
  __syncthreads();
}

__global__ void precompute_thin(const float* __restrict__ pred, int* __restrict__ out,
                                char* __restrict__ ws) {
  uint64_t* MASKW = (uint64_t*)(ws + T_MASK);
  uint64_t* UNCLW = (uint64_t*)(ws + T_UNCL);
  int* CTL = (int*)(ws + T_CTL);
  int gid = blockIdx.x * blockDim.x + threadIdx.x;
  int stride = gridDim.x * blockDim.x;
  for (int i = gid; i < NPIX; i += stride) {
    float smv = compute_sm(pred, i);
    unsigned long long bal = __ballot(smv > 0.5f);
    if ((threadIdx.x & 63) == 0) { MASKW[i >> 6] = bal; UNCLW[i >> 6] = bal; }
    out[i] = 0;
  }
  if (gid < TC_ZEND) CTL[gid] = 0;
}

__global__ __launch_bounds__(TPB) void cluster_thin(const float* __restrict__ pred,
                                                    int* __restrict__ out,
                                                    char* __restrict__ ws, int nblk) {
  uint64_t* MASKW = (uint64_t*)(ws + T_MASK);
  uint64_t* UNCLW = (uint64_t*)(ws + T_UNCL);
  uint64_t* P1W = (uint64_t*)(ws + T_P1);
  uint64_t* PV = (uint64_t*)(ws + T_PV);
  uint64_t* PSA = (uint64_t*)(ws + T_PSA);
  uint64_t* PSB = (uint64_t*)(ws + T_PSB);
  int* CTL = (int*)(ws + T_CTL);

  const int tid = threadIdx.x;
  const int lane = tid & 63;
  const int bid = blockIdx.x;
  const int nw = nblk * (TPB / 64);
  const int gw0 = bid * (TPB / 64) + (tid >> 6);

  __shared__ uint64_t lK[TPB / 64], lA[TPB / 64], lB[TPB / 64];
  __shared__ int lbin[256];
  __shared__ float s_cx[MAXI], s_cy[MAXI], s_sx[MAXI], s_sy[MAXI];
  __shared__ int s_sz[MAXI];

  int ph = 0;
  {
    int par = (ph + 1) & 1;
    uint64_t key = 0, sa = 0, sb = 0;
    for (int w = gw0; w < NWORD; w += nw) {
      uint64_t uw = UNCLW[w];
      if (!uw) continue;
      int i = (w << 6) | lane;
      if ((uw >> lane) & 1ull) {
        sa++;
        float v = compute_sm(pred, i);
        uint64_t k2 = ((uint64_t)(uint32_t)__float_as_int(v) << 32) | (uint32_t)~(uint32_t)i;
        if (k2 > key) key = k2;
      }
    }
    bred<TPB>(key, sa, sb, lK, lA, lB);
    if (tid == 0) {
      as64(&PV[par * T_NBLK + bid], key);
      as64(&PSA[par * T_NBLK + bid], sa);
      as64(&PSB[par * T_NBLK + bid], sb);
    }
  }
  gbar_rel(CTL, nblk, ++ph);
  float val1; int seed1; int Sall;
  {
    int par = ph & 1;
    uint64_t key, sa, sb;
    gred<TPB>(PV + par * T_NBLK, PSA + par * T_NBLK, PSB + par * T_NBLK, nblk,
              key, sa, sb, lK, lA, lB);
    val1 = __int_as_float((int)(key >> 32));
    seed1 = (int)~(uint32_t)key;
    Sall = (int)sa;
  }
  float cx1, cy1, sx1, sy1;
  {
    int bj = (seed1 >= 0 && seed1 < NPIX) ? seed1 : 0;
    compute_emb(pred, bj, cx1, cy1);
    sx1 = expf(pred[(size_t)2 * NPIX + bj] * 10.0f);
    sy1 = expf(pred[(size_t)3 * NPIX + bj] * 10.0f);
  }

  int count = 1, it = 0;
  while (Sall > 160 && count < 200 && it < 2000) {
    if (val1 < 0.5f) break;
    {
      int par = (ph + 1) & 1;
      uint64_t key = 0, sa = 0, sb = 0;
      for (int w = gw0; w < NWORD; w += nw) {
        uint64_t mw = MASKW[w];
        if (!mw) continue;
        int i = (w << 6) | lane;
        bool p = false;
        if ((mw >> lane) & 1ull) {
          float ex, ey; compute_emb(pred, i, ex, ey);
          p = prop_test(ex, ey, cx1, cy1, sx1, sy1);
        }
        uint64_t r = __ballot(p);
        if (lane == 0) P1W[w] = r;
        if (p) {
          sa++;
          float v = 1.0f / (1.0f + expf(-pred[(size_t)4 * NPIX + i]));
          uint64_t k2 = ((uint64_t)(uint32_t)__float_as_int(v) << 32) | (uint32_t)~(uint32_t)i;
          if (k2 > key) key = k2;
        }
      }
      bred<TPB>(key, sa, sb, lK, lA, lB);
      if (tid == 0) {
        as64(&PV[par * T_NBLK + bid], key);
        as64(&PSA[par * T_NBLK + bid], sa);
        as64(&PSB[par * T_NBLK + bid], sb);
      }
    }
    gbar_rel(CTL, nblk, ++ph);
    int seed2, cnt1;
    {
      int par = ph & 1;
      uint64_t key, sa, sb;
      gred<TPB>(PV + par * T_NBLK, PSA + par * T_NBLK, PSB + par * T_NBLK, nblk,
                key, sa, sb, lK, lA, lB);
      seed2 = (int)~(uint32_t)key;
      cnt1 = (int)sa;
    }
    bool big1 = cnt1 > 160;
    float cx2, cy2, sx2, sy2;
    {
      int bj = (seed2 >= 0 && seed2 < NPIX) ? seed2 : 0;
      compute_emb(pred, bj, cx2, cy2);
      sx2 = expf(pred[(size_t)2 * NPIX + bj] * 10.0f);
      sy2 = expf(pred[(size_t)3 * NPIX + bj] * 10.0f);
    }
    {
      int par = (ph + 1) & 1;
      uint64_t key = 0, sa = 0, sb = 0;
      for (int w = gw0; w < NWORD; w += nw) {
        uint64_t mw = MASKW[w];
        if (!mw) continue;
        uint64_t uw = UNCLW[w];
        uint64_t p1w = big1 ? 0ull : P1W[w];
        int i = (w << 6) | lane;
        bool p = false;
        if ((mw >> lane) & 1ull) {
          float ex, ey; compute_emb(pred, i, ex, ey);
          p = prop_test(ex, ey, cx2, cy2, sx2, sy2);
        }
        bool ub = ((uw >> lane) & 1ull) != 0;
        if (p) {
          sa += 1ull;
          if (ub && i != seed1 && !(big1 && i == seed2)) sa += (1ull << 32);
        }
        bool fp = big1 ? p : (((p1w >> lane) & 1ull) != 0);
        bool nu = ub && !(fp || i == seed1 || (big1 && i == seed2));
        uint64_t r = __ballot(nu);
        if (lane == 0 && uw) UNCLW[w] = r;
        if (nu) {
          sb++;
          float v = compute_sm(pred, i);
          uint64_t k2 = ((uint64_t)(uint32_t)__float_as_int(v) << 32) | (uint32_t)~(uint32_t)i;
          if (k2 > key) key = k2;
        }
      }
      bred<TPB>(key, sa, sb, lK, lA, lB);
      if (tid == 0) {
        as64(&PV[par * T_NBLK + bid], key);
        as64(&PSA[par * T_NBLK + bid], sa);
        as64(&PSB[par * T_NBLK + bid], sb);
      }
    }
    gbar_rel(CTL, nblk, ++ph);
    {
      int par = ph & 1;
      uint64_t key, sa, sb;
      gred<TPB>(PV + par * T_NBLK, PSA + par * T_NBLK, PSB + par * T_NBLK, nblk,
                key, sa, sb, lK, lA, lB);
      int cnt2 = (int)(uint32_t)sa;
      int ovl = (int)(uint32_t)(sa >> 32);
      bool big2 = cnt2 > 160;
      int den = cnt2 > 1 ? cnt2 : 1;
      float ratio = (float)ovl / (float)den;
      bool accept = big1 && big2 && (ratio > 0.5f);
      if (accept) {
        if (tid == 0) {
          s_cx[count] = cx2; s_cy[count] = cy2;
          s_sx[count] = sx2; s_sy[count] = sy2;
          s_sz[count] = cnt2;
        }
        count++;
      }
      it++;
      val1 = __int_as_float((int)(key >> 32));
      seed1 = (int)~(uint32_t)key;
      Sall = (int)sb;
    }
    {
      int bj = (seed1 >= 0 && seed1 < NPIX) ? seed1 : 0;
      compute_emb(pred, bj, cx1, cy1);
      sx1 = expf(pred[(size_t)2 * NPIX + bj] * 10.0f);
      sy1 = expf(pred[(size_t)3 * NPIX + bj] * 10.0f);
    }
  }

  lbin[tid] = 0;
  __syncthreads();
  for (int w = gw0; w < NWORD; w += nw) {
    uint64_t mw = MASKW[w];
    int i = (w << 6) | lane;
    int id = 0;
    if ((mw >> lane) & 1ull) {
      float ex, ey; compute_emb(pred, i, ex, ey);
      for (int k = 1; k < count; k++)
        if (prop_test(ex, ey, s_cx[k], s_cy[k], s_sx[k], s_sy[k])) id = k;
    }
    out[i] = id;
    atomicAdd(&lbin[id], 1);
  }
  __syncthreads();
  if (lbin[tid] > 0)
    __hip_atomic_fetch_add(&CTL[TC_NOW + tid], lbin[tid], __ATOMIC_RELAXED,
                           __HIP_MEMORY_SCOPE_AGENT);
  gbar_rel(CTL, nblk, ++ph);
  lbin[tid] = al(&CTL[TC_NOW + tid]);
  __syncthreads();
  for (int w = gw0; w < NWORD; w += nw) {
    int i = (w << 6) | lane;
    int id = out[i];
    if (id > 0) {
      int n = lbin[id];
      int sz = s_sz[id];
      bool rm = (n != sz) && ((n < 480) || ((float)n < 0.5f * (float)sz));
      if (rm) out[i] = 0;
    }
  }
}

static void launch_thin(const float* pred, int* out, char* ws, int numCU,
                        hipStream_t stream) {
  hipLaunchKernelGGL(precompute_thin, dim3(4096), dim3(TPB), 0, stream, pred, out, ws);
  int nblk = T_NBLK;
  int maxPerCU = 0;
  if (hipOccupancyMaxActiveBlocksPerMultiprocessor(&maxPerCU, (const void*)cluster_thin,
                                                   TPB, 0) == hipSuccess && maxPerCU > 0) {
    long long cap = (long long)maxPerCU * numCU;
    if (cap < nblk) nblk = (int)cap;
  }
  if (nblk < 1) nblk = 1;
  void* args[] = {(void*)&pred, (void*)&out, (void*)&ws, (void*)&nblk};
  hipLaunchCooperativeKernel((void*)cluster_thin, dim3(nblk), dim3(TPB), args, 0, stream);
}

extern "C" void kernel_launch(void* const* d_in, const int* in_sizes, int n_in,
                              void* d_out, int out_size, void* d_ws, size_t ws_size,
                              hipStream_t stream) {
  const float* pred = (const float*)d_in[0];
  int* out = (int*)d_out;
  char* ws = (char*)d_ws;

  int dev = 0;
  hipGetDevice(&dev);
  int numCU = 0;
  hipDeviceGetAttribute(&numCU, hipDeviceAttributeMultiprocessorCount, dev);
  if (numCU <= 0) numCU = 256;

  bool fat_ok = false;
  if (ws_size >= FAT_NEED) {
    int mpcC = 0, mpcP = 0;
    if (hipOccupancyMaxActiveBlocksPerMultiprocessor(&mpcC, (const void*)cluster_fat,
                                                     CTPB, 0) == hipSuccess &&
        hipOccupancyMaxActiveBlocksPerMultiprocessor(&mpcP, (const void*)preC_fat,
                                                     PTPB, 0) == hipSuccess &&
        (long long)mpcC * numCU >= NBLK &&
        (long long)mpcP * numCU >= PREB)   // preC co-residency required by its barrier
      fat_ok = true;
  }

  if (fat_ok) {
    hipMemsetAsync(ws + F_CTL, 0, FC_MEMSET_BYTES, stream);
    void* argsP[] = {(void*)&pred, (void*)&ws};
    hipLaunchCooperativeKernel((void*)preC_fat, dim3(PREB), dim3(PTPB), argsP, 0, stream);
    void* args[] = {(void*)&pred, (void*)&out, (void*)&ws};
    hipLaunchCooperativeKernel((void*)cluster_fat, dim3(NBLK), dim3(CTPB), args, 0, stream);
  } else {
    launch_thin(pred, out, ws, numCU, stream);
  }
}

// Round 15
// 275.507 us; speedup vs baseline: 2.7572x; 2.7572x over previous
//
#include <hip/hip_runtime.h>
#include <cfloat>
#include <climits>
#include <cstdint>

#define HH 1024
#define WW 2048
#define NPIX (HH * WW)
#define NWORD (NPIX / 64)
#define UNROLL 4
#define MAXI 200

#define BAND_LO 0.693130f
#define BAND_HI 0.693160f
#define LN2_CMP 0.6931472f

// ================= FAT layout =================
#define NBLK 256                     // cluster blocks
#define CTPB 512                     // cluster threads/block (8 waves)
#define PREB 1024                    // precompute blocks
#define PTPB 256
#define PWPB (NWORD / PREB)          // 32 words per precompute block
#define WPB  (NWORD / NBLK)          // 128 words per cluster block (recon map)
#define WPW  (WPB * 64 / CTPB)       // 16 words per wave in recon

#define F_CTL  ((size_t)0x0)         // 1024 slots x 128B; scalars/CSUM/NOW after
#define FC_CNT   32768               // int index
#define FC_A0KEY 32770               // u64 (8-aligned)
#define FC_NOW   32800               // 256 ints
#define FC_CSUM  33280               // 1024 ints
#define FC_MEMSET_BYTES ((size_t)0x22000)
#define F_PV   ((size_t)0x22000)     // 2 par x 256 u64
#define F_PSA  ((size_t)0x24000)
#define F_PSB  ((size_t)0x26000)
#define F_MASK ((size_t)0x40000)     // 256 KB mask bitwords
#define F_WOFF ((size_t)0x80000)     // 128 KB per-word compacted base
#define F_UNCL ((size_t)0xA0000)     // compacted uncl bits (wave-private, loop map)
#define F_P1C  ((size_t)0xE0000)     // compacted prop1 bits (wave-private, loop map)
#define CMAX   1220000
#define F_CEXY ((size_t)0x120000)                    // float2
#define F_CSV  (F_CEXY + (size_t)CMAX * 8 + 512)     // float
#define F_CSM  (F_CSV + (size_t)CMAX * 4 + 512)      // float
#define F_CS2  (F_CSM + (size_t)CMAX * 4 + 512)      // float2
#define FAT_NEED ((size_t)0x2200000)

// ================= THIN fallback (round-6 proven) =================
#define T_MASK ((size_t)0x0)
#define T_UNCL ((size_t)0x40000)
#define T_P1   ((size_t)0x80000)
#define T_PV   ((size_t)0xC0000)
#define T_PSA  ((size_t)0xC2000)
#define T_PSB  ((size_t)0xC4000)
#define T_CTL  ((size_t)0xD0000)
#define T_NBLK 256
#define TPB 256
#define TC_REL  8192
#define TC_NOW  8256
#define TC_ZEND 16384

// ---- relaxed agent-scope atomics: bypass non-coherent per-XCD L2, complete at
// the coherence point. No acq/rel -> no cache maintenance; ordering comes from
// vmcnt(0) drains + the slot observation chain.
__device__ __forceinline__ int al(const int* p) {
  return __hip_atomic_load((int*)p, __ATOMIC_RELAXED, __HIP_MEMORY_SCOPE_AGENT);
}
__device__ __forceinline__ void as_(int* p, int v) {
  __hip_atomic_store(p, v, __ATOMIC_RELAXED, __HIP_MEMORY_SCOPE_AGENT);
}
__device__ __forceinline__ uint64_t al64(const uint64_t* p) {
  return __hip_atomic_load((uint64_t*)p, __ATOMIC_RELAXED, __HIP_MEMORY_SCOPE_AGENT);
}
__device__ __forceinline__ void as64(uint64_t* p, uint64_t v) {
  __hip_atomic_store(p, v, __ATOMIC_RELAXED, __HIP_MEMORY_SCOPE_AGENT);
}

// seed_map = softmax(pred[5:7], axis=0)[1], op-for-op (max-subtract)
__device__ __forceinline__ float compute_sm(const float* __restrict__ pred, int i) {
  float a = pred[(size_t)5 * NPIX + i];
  float b = pred[(size_t)6 * NPIX + i];
  float m = fmaxf(a, b);
  float ea = expf(a - m);
  float eb = expf(b - m);
  return eb / (ea + eb);
}

__device__ __forceinline__ void compute_emb(const float* __restrict__ pred, int i,
                                            float& ex, float& ey) {
#pragma clang fp contract(off)
  int r = i >> 11;
  int c = i & (WW - 1);
  float xm = (float)c * (2.0f / 2047.0f);
  float ym = (float)r * (1.0f / 1023.0f);
  ex = tanhf(pred[i]) + xm;
  ey = tanhf(pred[(size_t)NPIX + i]) + ym;
}

// z in the reference's exact association; decision expf(-z)>0.5
__device__ __forceinline__ float prop_z(float ex, float ey, float cx, float cy,
                                        float sx, float sy) {
#pragma clang fp contract(off)
  float dx = ex - cx;
  float dy = ey - cy;
  float t0 = dx * dx; t0 = t0 * sx;
  float t1 = dy * dy; t1 = t1 * sy;
  return t0 + t1;
}

__device__ __forceinline__ bool prop_test(float ex, float ey, float cx, float cy,
                                          float sx, float sy) {
  float z = prop_z(ex, ey, cx, cy, sx, sy);
  return expf(-z) > 0.5f;
}

__device__ __forceinline__ uint64_t sh64(uint64_t v, int m) {
  return (uint64_t)__shfl_xor((unsigned long long)v, m, 64);
}

// block reduce: key = max (packed (val_bits<<32)|~idx), sa/sb u64 sums.
template <int T>
__device__ __forceinline__ void bred(uint64_t& key, uint64_t& sa, uint64_t& sb,
                                     uint64_t* lK, uint64_t* lA, uint64_t* lB) {
#pragma unroll
  for (int m = 1; m < 64; m <<= 1) {
    uint64_t k2 = sh64(key, m); if (k2 > key) key = k2;
    sa += sh64(sa, m);
    sb += sh64(sb, m);
  }
  int wid = threadIdx.x >> 6;
  if ((threadIdx.x & 63) == 0) { lK[wid] = key; lA[wid] = sa; lB[wid] = sb; }
  __syncthreads();
  key = lK[0]; sa = lA[0]; sb = lB[0];
#pragma unroll
  for (int w = 1; w < T / 64; w++) {
    uint64_t k2 = lK[w]; if (k2 > key) key = k2;
    sa += lA[w];
    sb += lB[w];
  }
  __syncthreads();
}

// redundant global reduce over per-block partials (every block, identical order)
template <int T>
__device__ __forceinline__ void gred(const uint64_t* PVp, const uint64_t* PAp,
                                     const uint64_t* PBp, int nblk,
                                     uint64_t& key, uint64_t& sa, uint64_t& sb,
                                     uint64_t* lK, uint64_t* lA, uint64_t* lB) {
  key = 0; sa = 0; sb = 0;
  for (int b = threadIdx.x; b < nblk; b += T) {
    uint64_t k2 = al64(&PVp[b]); if (k2 > key) key = k2;
    sa += al64(&PAp[b]);
    sb += al64(&PBp[b]);
  }
  bred<T>(key, sa, sb, lK, lA, lB);
}

// decentralized slot barrier: arrive (own slot), every block's wave 0 polls all.
__device__ __forceinline__ void gbar_d(int* CTL, int nblk, int ph) {
  __syncthreads();   // drains vmcnt -> prior stores L3-visible before slot store
  if (threadIdx.x == 0) {
    asm volatile("s_waitcnt vmcnt(0)" ::: "memory");
    as_(&CTL[blockIdx.x * 32], ph);
  }
  if (threadIdx.x < 64) {
    for (;;) {
      bool ok = true;
      for (int b = (int)threadIdx.x; b < nblk; b += 64)
        ok &= (al(&CTL[b * 32]) >= ph);
      if (__all(ok)) break;
      __builtin_amdgcn_s_sleep(1);
    }
    asm volatile("" ::: "memory");
  }
  __syncthreads();
}

// ============ FAT precompute: ONE cooperative kernel (plain-store scatter) ============
// 1024 blocks x 256 thr, all co-resident. Order-preserving compaction: block-
// private mask words (LDS), agent-posted chunk sums, slot barrier, redundant
// scan, then scatter with PLAIN stores (published by the kernel-end flush —
// the consumer is the NEXT kernel, so no agent atomics needed in the scatter).
__global__ __launch_bounds__(PTPB) void preC_fat(const float* __restrict__ pred,
                                                 char* __restrict__ ws) {
  uint64_t* MASKW = (uint64_t*)(ws + F_MASK);
  uint32_t* WOFF = (uint32_t*)(ws + F_WOFF);
  uint64_t* UNCLC = (uint64_t*)(ws + F_UNCL);
  float2* CEXY = (float2*)(ws + F_CEXY);
  float* CSV = (float*)(ws + F_CSV);
  float* CSM = (float*)(ws + F_CSM);
  float2* CS2 = (float2*)(ws + F_CS2);
  int* CTL = (int*)(ws + F_CTL);

  const int tid = threadIdx.x;
  const int lane = tid & 63;
  const int wv = tid >> 6;
  const int b = blockIdx.x;

  __shared__ uint64_t warr[PWPB];
  __shared__ int pcs[PWPB];
  __shared__ int lw[4];
  __shared__ int s_base;
  __shared__ int s_woff[PWPB];
  __shared__ uint64_t lKk[4];

  // phase 1: mask words for this block's 32-word chunk (block-private)
  for (int k = 0; k < PWPB / 4; k++) {
    int wl = wv * (PWPB / 4) + k;
    int w = b * PWPB + wl;
    int i = (w << 6) | lane;
    float smv = compute_sm(pred, i);
    uint64_t bal = __ballot(smv > 0.5f);
    if (lane == 0) { MASKW[w] = bal; warr[wl] = bal; pcs[wl] = (int)__popcll(bal); }
  }
  // UNCLC bulk all-ones (tail beyond cnt handled by j<cnt guard in pass C)
  {
    int gid = b * PTPB + tid;
    for (int w = gid; w < (CMAX + 63) / 64; w += PREB * PTPB) UNCLC[w] = ~0ull;
  }
  __syncthreads();
  if (tid == 0) {
    int t = 0;
#pragma unroll
    for (int k = 0; k < PWPB; k++) t += pcs[k];
    as_(&CTL[FC_CSUM + b], t);       // agent: read cross-block after barrier
  }
  gbar_d(CTL, PREB, 1);

  // phase 2: redundant scan of 1024 chunk sums -> own base
  {
    int base4[4];
    int s = 0;
#pragma unroll
    for (int k = 0; k < 4; k++) {
      int v = al(&CTL[FC_CSUM + tid * 4 + k]);
      base4[k] = s; s += v;
    }
    int inc = s;
#pragma unroll
    for (int off = 1; off < 64; off <<= 1) {
      int v = __shfl_up(inc, off, 64);
      if (lane >= off) inc += v;
    }
    if (lane == 63) lw[wv] = inc;
    __syncthreads();
    if (tid == 0) {
      int run = 0;
#pragma unroll
      for (int k = 0; k < 4; k++) { int v = lw[k]; lw[k] = run; run += v; }
      if (b == 0) CTL[FC_CNT] = run;   // plain: consumed by next kernel
    }
    __syncthreads();
    int excl = lw[wv] + inc - s;       // exclusive prefix of this thread's group
#pragma unroll
    for (int k = 0; k < 4; k++)
      if (tid * 4 + k == b) s_base = excl + base4[k];
  }
  __syncthreads();
  // per-word exclusive offsets within the chunk (lane-scan over 32 counts)
  if (tid < PWPB) {
    int pc = pcs[tid];
    int inc = pc;
#pragma unroll
    for (int off = 1; off < PWPB; off <<= 1) {
      int v = __shfl_up(inc, off, 32);
      if (tid >= off) inc += v;
    }
    int excl = s_base + inc - pc;
    s_woff[tid] = excl;
    WOFF[b * PWPB + tid] = (uint32_t)excl;   // plain
  }
  __syncthreads();

  // scatter SoA (plain stores) + A0 argmax fold
  uint64_t key = 0;
  for (int k = 0; k < PWPB / 4; k++) {
    int wl = wv * (PWPB / 4) + k;
    int w = b * PWPB + wl;
    uint64_t mw = warr[wl];
    if ((mw >> lane) & 1ull) {
      int i = (w << 6) | lane;
      int j = s_woff[wl] + (int)__popcll(mw & ((1ull << lane) - 1ull));
      if (j < CMAX) {
        float ex, ey; compute_emb(pred, i, ex, ey);
        float smv = compute_sm(pred, i);
        float sv = 1.0f / (1.0f + expf(-pred[(size_t)4 * NPIX + i]));
        float sx = expf(pred[(size_t)2 * NPIX + i] * 10.0f);
        float sy = expf(pred[(size_t)3 * NPIX + i] * 10.0f);
        CEXY[j] = make_float2(ex, ey);
        CSV[j] = sv;
        CSM[j] = smv;
        CS2[j] = make_float2(sx, sy);
        uint64_t k2 = ((uint64_t)(uint32_t)__float_as_int(smv) << 32) | (uint32_t)~(uint32_t)j;
        if (k2 > key) key = k2;
      }
    }
  }
#pragma unroll
  for (int m = 1; m < 64; m <<= 1) {
    uint64_t k2 = sh64(key, m); if (k2 > key) key = k2;
  }
  if (lane == 0) lKk[wv] = key;
  __syncthreads();
  if (tid == 0) {
    uint64_t k = lKk[0];
#pragma unroll
    for (int w = 1; w < 4; w++) if (lKk[w] > k) k = lKk[w];
    if (k) __hip_atomic_fetch_max((unsigned long long*)&CTL[FC_A0KEY], (unsigned long long)k,
                                  __ATOMIC_RELAXED, __HIP_MEMORY_SCOPE_AGENT);
  }
}

// ======================= FAT main cooperative kernel (512 thr x 256 blk) =======================
__global__ __launch_bounds__(CTPB) void cluster_fat(const float* __restrict__ pred,
                                                    int* __restrict__ out,
                                                    char* __restrict__ ws) {
  uint64_t* MASKW = (uint64_t*)(ws + F_MASK);
  uint32_t* WOFF = (uint32_t*)(ws + F_WOFF);
  uint64_t* UNCLC = (uint64_t*)(ws + F_UNCL);
  uint64_t* P1C = (uint64_t*)(ws + F_P1C);
  uint64_t* PV = (uint64_t*)(ws + F_PV);
  uint64_t* PSA = (uint64_t*)(ws + F_PSA);
  uint64_t* PSB = (uint64_t*)(ws + F_PSB);
  int* CTL = (int*)(ws + F_CTL);
  const float2* __restrict__ CEXY = (const float2*)(ws + F_CEXY);
  const float* __restrict__ CSV = (const float*)(ws + F_CSV);
  const float* __restrict__ CSM = (const float*)(ws + F_CSM);
  const float2* __restrict__ CS2 = (const float2*)(ws + F_CS2);

  const int tid = threadIdx.x;
  const int lane = tid & 63;
  const int wid = tid >> 6;
  const int bid = blockIdx.x;
  const int nw = NBLK * (CTPB / 64);        // 2048 waves
  const int gw0 = bid * (CTPB / 64) + wid;

  __shared__ uint64_t lK[CTPB / 64], lA[CTPB / 64], lB[CTPB / 64];
  __shared__ int lbin[256];
  __shared__ float s_cx[MAXI], s_cy[MAXI], s_sx[MAXI], s_sy[MAXI];
  __shared__ int s_sz[MAXI];

  int cnt = al(&CTL[FC_CNT]);
  if (cnt > CMAX) cnt = CMAX;
  const int cnw = (cnt + 63) >> 6;

  int ph = 1;   // preC_fat consumed phase 1 on slots 0..255

  // A0 from preC_fat's atomic max
  uint64_t akey = al64((const uint64_t*)&CTL[FC_A0KEY]);
  float val1 = __int_as_float((int)(akey >> 32));
  int seed1 = (int)~(uint32_t)akey;
  int Sall = cnt;
  float cx1, cy1, sx1, sy1;
  {
    int j = (seed1 >= 0 && seed1 < cnt) ? seed1 : 0;
    float2 e = CEXY[j]; float2 r = CS2[j];
    cx1 = e.x; cy1 = e.y; sx1 = r.x; sy1 = r.y;
  }

  int count = 1, it = 0;
  while (Sall > 160 && count < 200 && it < 2000) {
    if (val1 < 0.5f) break;   // 'stop': freeze state

    // ---- pass B: prop1 bits, cnt1, seed2 = argmax(sv | prop1) ----
    {
      int par = (ph + 1) & 1;
      uint64_t key = 0, sa = 0, sb = 0;
      for (int w0 = gw0; w0 < cnw; w0 += nw * UNROLL) {
#pragma unroll
        for (int u = 0; u < UNROLL; u++) {
          int w = w0 + u * nw;
          if (w >= cnw) continue;
          int j = (w << 6) | lane;
          float z = 1e30f;
          if (j < cnt) {
            float2 e = CEXY[j];
            z = prop_z(e.x, e.y, cx1, cy1, sx1, sy1);
          }
          bool band = (z > BAND_LO) & (z < BAND_HI);
          bool p;
          if (__any(band)) p = (j < cnt) && (expf(-z) > 0.5f);
          else p = z < LN2_CMP;
          uint64_t r = __ballot(p);
          if (lane == 0) P1C[w] = r;   // plain: wave-private
          if (p) {
            sa++;
            float sv = CSV[j];          // gated: only prop1 members
            uint64_t k2 = ((uint64_t)(uint32_t)__float_as_int(sv) << 32) | (uint32_t)~(uint32_t)j;
            if (k2 > key) key = k2;
          }
        }
      }
      bred<CTPB>(key, sa, sb, lK, lA, lB);
      if (tid == 0) {
        as64(&PV[par * NBLK + bid], key);
        as64(&PSA[par * NBLK + bid], sa);
        as64(&PSB[par * NBLK + bid], sb);
      }
    }
    gbar_d(CTL, NBLK, ++ph);
    int seed2, cnt1;
    {
      int par = ph & 1;
      uint64_t key, sa, sb;
      gred<CTPB>(PV + par * NBLK, PSA + par * NBLK, PSB + par * NBLK, NBLK,
                 key, sa, sb, lK, lA, lB);
      seed2 = (int)~(uint32_t)key;
      cnt1 = (int)sa;
    }
    bool big1 = cnt1 > 160;
    float cx2, cy2, sx2, sy2;
    {
      int j = (seed2 >= 0 && seed2 < cnt) ? seed2 : 0;
      float2 e = CEXY[j]; float2 r = CS2[j];
      cx2 = e.x; cy2 = e.y; sx2 = r.x; sy2 = r.y;
    }

    // ---- pass C (fused): prop2 counts/overlap (seed corrections inline) +
    //      uncl update + next-iteration argmax/sum ----
    {
      int par = (ph + 1) & 1;
      uint64_t key = 0, sa = 0, sb = 0;
      for (int w0 = gw0; w0 < cnw; w0 += nw * UNROLL) {
#pragma unroll
        for (int u = 0; u < UNROLL; u++) {
          int w = w0 + u * nw;
          if (w >= cnw) continue;
          uint64_t uw = UNCLC[w];                 // plain: wave-private
          uint64_t p1w = big1 ? 0ull : P1C[w];
          int j = (w << 6) | lane;
          float z = 1e30f;
          if (j < cnt) {
            float2 e = CEXY[j];
            z = prop_z(e.x, e.y, cx2, cy2, sx2, sy2);
          }
          bool band = (z > BAND_LO) & (z < BAND_HI);
          bool p;
          if (__any(band)) p = (j < cnt) && (expf(-z) > 0.5f);
          else p = z < LN2_CMP;
          bool ub = ((uw >> lane) & 1ull) != 0;
          // reference clears uncl at seed1 (always) and seed2 (if big1) BEFORE
          // the overlap sum -> owning lane doesn't count its overlap.
          if (p) {
            sa += 1ull;
            if (ub && j != seed1 && !(big1 && j == seed2)) sa += (1ull << 32);
          }
          bool fp = big1 ? p : (((p1w >> lane) & 1ull) != 0);
          bool nu = ub && (j < cnt) && !(fp || j == seed1 || (big1 && j == seed2));
          uint64_t r = __ballot(nu);
          if (lane == 0 && uw) UNCLC[w] = r;      // plain: wave-private
          if (nu) {
            sb++;
            float smv = CSM[j];                    // gated: only uncl survivors
            uint64_t k2 = ((uint64_t)(uint32_t)__float_as_int(smv) << 32) | (uint32_t)~(uint32_t)j;
            if (k2 > key) key = k2;
          }
        }
      }
      bred<CTPB>(key, sa, sb, lK, lA, lB);
      if (tid == 0) {
        as64(&PV[par * NBLK + bid], key);
        as64(&PSA[par * NBLK + bid], sa);
        as64(&PSB[par * NBLK + bid], sb);
      }
    }
    gbar_d(CTL, NBLK, ++ph);
    {
      int par = ph & 1;
      uint64_t key, sa, sb;
      gred<CTPB>(PV + par * NBLK, PSA + par * NBLK, PSB + par * NBLK, NBLK,
                 key, sa, sb, lK, lA, lB);
      int cnt2 = (int)(uint32_t)sa;
      int ovl = (int)(uint32_t)(sa >> 32);
      bool big2 = cnt2 > 160;
      int den = cnt2 > 1 ? cnt2 : 1;
      float ratio = (float)ovl / (float)den;
      bool accept = big1 && big2 && (ratio > 0.5f);
      if (accept) {
        if (tid == 0) {
          s_cx[count] = cx2; s_cy[count] = cy2;
          s_sx[count] = sx2; s_sy[count] = sy2;
          s_sz[count] = cnt2;
        }
        count++;
      }
      it++;
      val1 = __int_as_float((int)(key >> 32));
      seed1 = (int)~(uint32_t)key;
      Sall = (int)sb;
    }
    {
      int j = (seed1 >= 0 && seed1 < cnt) ? seed1 : 0;
      float2 e = CEXY[j]; float2 r = CS2[j];
      cx1 = e.x; cy1 = e.y; sx1 = r.x; sy1 = r.y;
    }
  }

  // ---- reconstruction (pixel space, contiguous map): out + zero-fill + bincount ----
  if (tid < 256) lbin[tid] = 0;
  __syncthreads();   // publishes tid0's s_* log writes block-wide
  for (int k = 0; k < WPW; k++) {
    int w = bid * WPB + wid * WPW + k;
    uint64_t mw = MASKW[w];
    int i = (w << 6) | lane;
    int id = 0;
    if ((mw >> lane) & 1ull) {
      int j = (int)WOFF[w] + (int)__popcll(mw & ((1ull << lane) - 1ull));
      if (j < CMAX) {
        float2 e = CEXY[j];
        for (int kk = 1; kk < count; kk++) {
          float z = prop_z(e.x, e.y, s_cx[kk], s_cy[kk], s_sx[kk], s_sy[kk]);
          bool band = (z > BAND_LO) & (z < BAND_HI);
          bool p;
          if (__any(band)) p = expf(-z) > 0.5f;
          else p = z < LN2_CMP;
          if (p) id = kk;
        }
      }
      atomicAdd(&lbin[id], 1);
    }
    out[i] = id;   // full-word coalesced store (zero-fill fused)
  }
  __syncthreads();
  if (tid < 256 && lbin[tid] > 0)
    __hip_atomic_fetch_add(&CTL[FC_NOW + tid], lbin[tid], __ATOMIC_RELAXED,
                           __HIP_MEMORY_SCOPE_AGENT);
  gbar_d(CTL, NBLK, ++ph);
  if (tid < 256) lbin[tid] = al(&CTL[FC_NOW + tid]);
  __syncthreads();
  for (int k = 0; k < WPW; k++) {
    int w = bid * WPB + wid * WPW + k;
    int i = (w << 6) | lane;
    int id = out[i];   // plain: same wave wrote it
    if (id > 0) {
      int n = lbin[id];
      int sz = s_sz[id];
      bool rm = (n != sz) && ((n < 480) || ((float)n < 0.5f * (float)sz));
      if (rm) out[i] = 0;
    }
  }
}

// ======================= THIN fallback (round-6, proven) =======================
__device__ __forceinline__ void gbar_rel(int* CTL, int nblk, int ph) {
  __syncthreads();
  if (threadIdx.x == 0) {
    asm volatile("s_waitcnt vmcnt(0)" ::: "memory");
    as_(&CTL[blockIdx.x * 32], ph);
  }
  if (blockIdx.x == 0) {
    if (threadIdx.x < 64) {
      for (;;) {
        bool ok = true;
        for (int b = (int)threadIdx.x; b < nblk; b += 64)
          ok &= (al(&CTL[b * 32]) >= ph);
        if (__all(ok)) break;
        __builtin_amdgcn_s_sleep(1);
      }
      asm volatile("" ::: "memory");
      if (threadIdx.x == 0) as_(&CTL[TC_REL], ph);
    }
  } else {
    if (threadIdx.x == 0) {
      while (al(&CTL[TC_REL]) < ph) __builtin_amdgcn_s_sleep(1);
      asm volatile("" ::: "memory");
    }
  }
  __syncthreads();
}

__global__ void precompute_thin(const float* __restrict__ pred, int* __restrict__ out,
                                char* __restrict__ ws) {
  uint64_t* MASKW = (uint64_t*)(ws + T_MASK);
  uint64_t* UNCLW = (uint64_t*)(ws + T_UNCL);
  int* CTL = (int*)(ws + T_CTL);
  int gid = blockIdx.x * blockDim.x + threadIdx.x;
  int stride = gridDim.x * blockDim.x;
  for (int i = gid; i < NPIX; i += stride) {
    float smv = compute_sm(pred, i);
    unsigned long long bal = __ballot(smv > 0.5f);
    if ((threadIdx.x & 63) == 0) { MASKW[i >> 6] = bal; UNCLW[i >> 6] = bal; }
    out[i] = 0;
  }
  if (gid < TC_ZEND) CTL[gid] = 0;
}

__global__ __launch_bounds__(TPB) void cluster_thin(const float* __restrict__ pred,
                                                    int* __restrict__ out,
                                                    char* __restrict__ ws, int nblk) {
  uint64_t* MASKW = (uint64_t*)(ws + T_MASK);
  uint64_t* UNCLW = (uint64_t*)(ws + T_UNCL);
  uint64_t* P1W = (uint64_t*)(ws + T_P1);
  uint64_t* PV = (uint64_t*)(ws + T_PV);
  uint64_t* PSA = (uint64_t*)(ws + T_PSA);
  uint64_t* PSB = (uint64_t*)(ws + T_PSB);
  int* CTL = (int*)(ws + T_CTL);

  const int tid = threadIdx.x;
  const int lane = tid & 63;
  const int bid = blockIdx.x;
  const int nw = nblk * (TPB / 64);
  const int gw0 = bid * (TPB / 64) + (tid >> 6);

  __shared__ uint64_t lK[TPB / 64], lA[TPB / 64], lB[TPB / 64];
  __shared__ int lbin[256];
  __shared__ float s_cx[MAXI], s_cy[MAXI], s_sx[MAXI], s_sy[MAXI];
  __shared__ int s_sz[MAXI];

  int ph = 0;
  {
    int par = (ph + 1) & 1;
    uint64_t key = 0, sa = 0, sb = 0;
    for (int w = gw0; w < NWORD; w += nw) {
      uint64_t uw = UNCLW[w];
      if (!uw) continue;
      int i = (w << 6) | lane;
      if ((uw >> lane) & 1ull) {
        sa++;
        float v = compute_sm(pred, i);
        uint64_t k2 = ((uint64_t)(uint32_t)__float_as_int(v) << 32) | (uint32_t)~(uint32_t)i;
        if (k2 > key) key = k2;
      }
    }
    bred<TPB>(key, sa, sb, lK, lA, lB);
    if (tid == 0) {
      as64(&PV[par * T_NBLK + bid], key);
      as64(&PSA[par * T_NBLK + bid], sa);
      as64(&PSB[par * T_NBLK + bid], sb);
    }
  }
  gbar_rel(CTL, nblk, ++ph);
  float val1; int seed1; int Sall;
  {
    int par = ph & 1;
    uint64_t key, sa, sb;
    gred<TPB>(PV + par * T_NBLK, PSA + par * T_NBLK, PSB + par * T_NBLK, nblk,
              key, sa, sb, lK, lA, lB);
    val1 = __int_as_float((int)(key >> 32));
    seed1 = (int)~(uint32_t)key;
    Sall = (int)sa;
  }
  float cx1, cy1, sx1, sy1;
  {
    int bj = (seed1 >= 0 && seed1 < NPIX) ? seed1 : 0;
    compute_emb(pred, bj, cx1, cy1);
    sx1 = expf(pred[(size_t)2 * NPIX + bj] * 10.0f);
    sy1 = expf(pred[(size_t)3 * NPIX + bj] * 10.0f);
  }

  int count = 1, it = 0;
  while (Sall > 160 && count < 200 && it < 2000) {
    if (val1 < 0.5f) break;
    {
      int par = (ph + 1) & 1;
      uint64_t key = 0, sa = 0, sb = 0;
      for (int w = gw0; w < NWORD; w += nw) {
        uint64_t mw = MASKW[w];
        if (!mw) continue;
        int i = (w << 6) | lane;
        bool p = false;
        if ((mw >> lane) & 1ull) {
          float ex, ey; compute_emb(pred, i, ex, ey);
          p = prop_test(ex, ey, cx1, cy1, sx1, sy1);
        }
        uint64_t r = __ballot(p);
        if (lane == 0) P1W[w] = r;
        if (p) {
          sa++;
          float v = 1.0f / (1.0f + expf(-pred[(size_t)4 * NPIX + i]));
          uint64_t k2 = ((uint64_t)(uint32_t)__float_as_int(v) << 32) | (uint32_t)~(uint32_t)i;
          if (k2 > key) key = k2;
        }
      }
      bred<TPB>(key, sa, sb, lK, lA, lB);
      if (tid == 0) {
        as64(&PV[par * T_NBLK + bid], key);
        as64(&PSA[par * T_NBLK + bid], sa);
        as64(&PSB[par * T_NBLK + bid], sb);
      }
    }
    gbar_rel(CTL, nblk, ++ph);
    int seed2, cnt1;
    {
      int par = ph & 1;
      uint64_t key, sa, sb;
      gred<TPB>(PV + par * T_NBLK, PSA + par * T_NBLK, PSB + par * T_NBLK, nblk,
                key, sa, sb, lK, lA, lB);
      seed2 = (int)~(uint32_t)key;
      cnt1 = (int)sa;
    }
    bool big1 = cnt1 > 160;
    float cx2, cy2, sx2, sy2;
    {
      int bj = (seed2 >= 0 && seed2 < NPIX) ? seed2 : 0;
      compute_emb(pred, bj, cx2, cy2);
      sx2 = expf(pred[(size_t)2 * NPIX + bj] * 10.0f);
      sy2 = expf(pred[(size_t)3 * NPIX + bj] * 10.0f);
    }
    {
      int par = (ph + 1) & 1;
      uint64_t key = 0, sa = 0, sb = 0;
      for (int w = gw0; w < NWORD; w += nw) {
        uint64_t mw = MASKW[w];
        if (!mw) continue;
        uint64_t uw = UNCLW[w];
        uint64_t p1w = big1 ? 0ull : P1W[w];
        int i = (w << 6) | lane;
        bool p = false;
        if ((mw >> lane) & 1ull) {
          float ex, ey; compute_emb(pred, i, ex, ey);
          p = prop_test(ex, ey, cx2, cy2, sx2, sy2);
        }
        bool ub = ((uw >> lane) & 1ull) != 0;
        if (p) {
          sa += 1ull;
          if (ub && i != seed1 && !(big1 && i == seed2)) sa += (1ull << 32);
        }
        bool fp = big1 ? p : (((p1w >> lane) & 1ull) != 0);
        bool nu = ub && !(fp || i == seed1 || (big1 && i == seed2));
        uint64_t r = __ballot(nu);
        if (lane == 0 && uw) UNCLW[w] = r;
        if (nu) {
          sb++;
          float v = compute_sm(pred, i);
          uint64_t k2 = ((uint64_t)(uint32_t)__float_as_int(v) << 32) | (uint32_t)~(uint32_t)i;
          if (k2 > key) key = k2;
        }
      }
      bred<TPB>(key, sa, sb, lK, lA, lB);
      if (tid == 0) {
        as64(&PV[par * T_NBLK + bid], key);
        as64(&PSA[par * T_NBLK + bid], sa);
        as64(&PSB[par * T_NBLK + bid], sb);
      }
    }
    gbar_rel(CTL, nblk, ++ph);
    {
      int par = ph & 1;
      uint64_t key, sa, sb;
      gred<TPB>(PV + par * T_NBLK, PSA + par * T_NBLK, PSB + par * T_NBLK, nblk,
                key, sa, sb, lK, lA, lB);
      int cnt2 = (int)(uint32_t)sa;
      int ovl = (int)(uint32_t)(sa >> 32);
      bool big2 = cnt2 > 160;
      int den = cnt2 > 1 ? cnt2 : 1;
      float ratio = (float)ovl / (float)den;
      bool accept = big1 && big2 && (ratio > 0.5f);
      if (accept) {
        if (tid == 0) {
          s_cx[count] = cx2; s_cy[count] = cy2;
          s_sx[count] = sx2; s_sy[count] = sy2;
          s_sz[count] = cnt2;
        }
        count++;
      }
      it++;
      val1 = __int_as_float((int)(key >> 32));
      seed1 = (int)~(uint32_t)key;
      Sall = (int)sb;
    }
    {
      int bj = (seed1 >= 0 && seed1 < NPIX) ? seed1 : 0;
      compute_emb(pred, bj, cx1, cy1);
      sx1 = expf(pred[(size_t)2 * NPIX + bj] * 10.0f);
      sy1 = expf(pred[(size_t)3 * NPIX + bj] * 10.0f);
    }
  }

  lbin[tid] = 0;
  __syncthreads();
  for (int w = gw0; w < NWORD; w += nw) {
    uint64_t mw = MASKW[w];
    int i = (w << 6) | lane;
    int id = 0;
    if ((mw >> lane) & 1ull) {
      float ex, ey; compute_emb(pred, i, ex, ey);
      for (int k = 1; k < count; k++)
        if (prop_test(ex, ey, s_cx[k], s_cy[k], s_sx[k], s_sy[k])) id = k;
    }
    out[i] = id;
    atomicAdd(&lbin[id], 1);
  }
  __syncthreads();
  if (lbin[tid] > 0)
    __hip_atomic_fetch_add(&CTL[TC_NOW + tid], lbin[tid], __ATOMIC_RELAXED,
                           __HIP_MEMORY_SCOPE_AGENT);
  gbar_rel(CTL, nblk, ++ph);
  lbin[tid] = al(&CTL[TC_NOW + tid]);
  __syncthreads();
  for (int w = gw0; w < NWORD; w += nw) {
    int i = (w << 6) | lane;
    int id = out[i];
    if (id > 0) {
      int n = lbin[id];
      int sz = s_sz[id];
      bool rm = (n != sz) && ((n < 480) || ((float)n < 0.5f * (float)sz));
      if (rm) out[i] = 0;
    }
  }
}

static void launch_thin(const float* pred, int* out, char* ws, int numCU,
                        hipStream_t stream) {
  hipLaunchKernelGGL(precompute_thin, dim3(4096), dim3(TPB), 0, stream, pred, out, ws);
  int nblk = T_NBLK;
  int maxPerCU = 0;
  if (hipOccupancyMaxActiveBlocksPerMultiprocessor(&maxPerCU, (const void*)cluster_thin,
                                                   TPB, 0) == hipSuccess && maxPerCU > 0) {
    long long cap = (long long)maxPerCU * numCU;
    if (cap < nblk) nblk = (int)cap;
  }
  if (nblk < 1) nblk = 1;
  void* args[] = {(void*)&pred, (void*)&out, (void*)&ws, (void*)&nblk};
  hipLaunchCooperativeKernel((void*)cluster_thin, dim3(nblk), dim3(TPB), args, 0, stream);
}

extern "C" void kernel_launch(void* const* d_in, const int* in_sizes, int n_in,
                              void* d_out, int out_size, void* d_ws, size_t ws_size,
                              hipStream_t stream) {
  const float* pred = (const float*)d_in[0];
  int* out = (int*)d_out;
  char* ws = (char*)d_ws;

  int dev = 0;
  hipGetDevice(&dev);
  int numCU = 0;
  hipDeviceGetAttribute(&numCU, hipDeviceAttributeMultiprocessorCount, dev);
  if (numCU <= 0) numCU = 256;

  bool fat_ok = false;
  if (ws_size >= FAT_NEED) {
    int mpcC = 0, mpcP = 0;
    if (hipOccupancyMaxActiveBlocksPerMultiprocessor(&mpcC, (const void*)cluster_fat,
                                                     CTPB, 0) == hipSuccess &&
        hipOccupancyMaxActiveBlocksPerMultiprocessor(&mpcP, (const void*)preC_fat,
                                                     PTPB, 0) == hipSuccess &&
        (long long)mpcC * numCU >= NBLK &&
        (long long)mpcP * numCU >= PREB)   // preC co-residency required by its barrier
      fat_ok = true;
  }

  if (fat_ok) {
    hipMemsetAsync(ws + F_CTL, 0, FC_MEMSET_BYTES, stream);
    void* argsP[] = {(void*)&pred, (void*)&ws};
    hipLaunchCooperativeKernel((void*)preC_fat, dim3(PREB), dim3(PTPB), argsP, 0, stream);
    void* args[] = {(void*)&pred, (void*)&out, (void*)&ws};
    hipLaunchCooperativeKernel((void*)cluster_fat, dim3(NBLK), dim3(CTPB), args, 0, stream);
  } else {
    launch_thin(pred, out, ws, numCU, stream);
  }
}